// Round 14
// baseline (48.378 us; speedup 1.0000x reference)
//
#include <hip/hip_runtime.h>
#include <hip/hip_bf16.h>

// out = x @ Mtot + btot;  Mtot = L(in_W) @ out_W  (meas_ops == eye, exact skip)
// K_prep (256 blocks): 2 rows/block of W1f = L(in_W rows); blk 0 also bvec = L(in_b)
// K_mid  (256 blocks): one 32x32 MtotT tile each; blocks 0..15 also btot
// K_main (256x4 blocks): out = x @ Mtot + btot (BM=64 x BN=128, 3 blocks/CU)

typedef float  fvec4 __attribute__((ext_vector_type(4)));
typedef float  f32x4 __attribute__((ext_vector_type(4)));
typedef short  short8 __attribute__((ext_vector_type(8)));
typedef unsigned short us8 __attribute__((ext_vector_type(8)));
typedef unsigned short us4 __attribute__((ext_vector_type(4)));

#define H 512
#define NL 3

__device__ __forceinline__ unsigned short f2bf(float f) {
    return __bfloat16_as_ushort(__float2bfloat16(f));
}
__device__ __forceinline__ float bf2f(unsigned short u) {
    return __uint_as_float((unsigned int)u << 16);
}
__device__ __forceinline__ void gll16(const void* g, void* l) {
    __builtin_amdgcn_global_load_lds((const __attribute__((address_space(1))) void*)g,
                                     (__attribute__((address_space(3))) void*)l, 16, 0, 0);
}
// 16B-chunk XOR swizzle for 1024B rows (bijective within row)
__device__ __forceinline__ int swz1024(int r, int byte) {
    return r * 1024 + (((byte >> 4) ^ (r & 7)) << 4) + (byte & 15);
}

// ---------------------------------------------------------------------------
// K_prep: 256 blocks; block bx -> rows 2bx, 2bx+1 (256 thr each);
//         block 0 second pass -> bvec = L(in_b).  (R12-S1 verified structure)
// ---------------------------------------------------------------------------
__global__ __launch_bounds__(512) void k_prep(const float* __restrict__ in_W,
                                              const float* __restrict__ in_b,
                                              const float* __restrict__ entW,
                                              const float* __restrict__ strength,
                                              const float* __restrict__ supW,
                                              const float* __restrict__ coeffs,
                                              const float* __restrict__ cp,
                                              float* __restrict__ W1f,
                                              float* __restrict__ bvec) {
    __shared__ float sseg[2][H];
    __shared__ float sval[2][H];
    __shared__ float sw[H];
    const int bx = blockIdx.x;
    const int tid = threadIdx.x;
    const float is2 = 0.70710678118654752440f;

    float wacc = 0.f;
#pragma unroll
    for (int s = 0; s < 8; ++s) wacc += coeffs[s] * supW[s * H + tid];
    sw[tid] = wacc;
    const int half = tid >> 8, t = tid & 255;

    for (int pass = 0; pass < 2; ++pass) {
        const bool active = (pass == 0) || (bx == 0 && half == 0);
        const int r = 2 * bx + half;
        const float* src = (pass == 0) ? (in_W + (size_t)r * H) : in_b;
        float* dst = (pass == 0) ? (W1f + (size_t)r * H) : bvec;
        __syncthreads();
        if (active) {
            sseg[half][t] = src[t];
            sseg[half][256 + t] = src[256 + t];
        }
        __syncthreads();
        if (active) {
#pragma unroll
            for (int cc = 0; cc < 2; ++cc) {
                const int c = t + cc * 256;
                const int p = c >> 7, j = c & 127;
                const int jsrc = (j & 2) ? (j ^ 1) : j;
                const float* wcol = entW + p * 16384 + jsrc;
                const float* seg = &sseg[half][p * 128];
                float a0 = 0.f, a1 = 0.f, a2 = 0.f, a3 = 0.f;
#pragma unroll 4
                for (int i = 0; i < 128; i += 4) {
                    a0 += seg[i + 0] * wcol[(i + 0) * 128];
                    a1 += seg[i + 1] * wcol[(i + 1) * 128];
                    a2 += seg[i + 2] * wcol[(i + 2) * 128];
                    a3 += seg[i + 3] * wcol[(i + 3) * 128];
                }
                sval[half][c] = ((a0 + a1) + (a2 + a3)) * strength[p];
            }
        }
        __syncthreads();
        if (active) {
#pragma unroll
            for (int cc = 0; cc < 2; ++cc) {
                const int c = t + cc * 256;
                const int q4 = c & ~3;
                float v0 = sval[half][q4], v1 = sval[half][q4 + 1];
                float v2 = sval[half][q4 + 2], v3 = sval[half][q4 + 3];
                float t0, t1, t2, t3;
                t0 = (v0 + v1) * is2; t1 = (v0 - v1) * is2;
                t2 = (v2 + v3) * is2; t3 = (v2 - v3) * is2;
                v0 = t0 * sw[q4]; v1 = t1 * sw[q4 + 1];
                v2 = t2 * sw[q4 + 2]; v3 = t3 * sw[q4 + 3];
                const int qb = c >> 6;
#pragma unroll
                for (int l = 0; l < NL; ++l) {
                    float px = cp[l * 24 + qb * 3 + 0];
                    float pz = cp[l * 24 + qb * 3 + 2];
                    t0 = (v0 + v1) * is2; t1 = (v0 - v1) * is2;
                    t2 = (v2 + v3) * is2; t3 = (v2 - v3) * is2;
                    v0 = t0; v1 = t1; v2 = t2; v3 = t3;
                    t0 = v0 + px * v1; t1 = v1 + px * v0;
                    t2 = v2 + px * v3; t3 = v3 + px * v2;
                    v0 = t0; v1 = t1; v2 = t2; v3 = t3;
                    v0 *= (1.f + pz); v1 *= (1.f - pz);
                    v2 *= (1.f + pz); v3 *= (1.f - pz);
                    t0 = v2; v2 = v3; v3 = t0;   // CNOT
                }
                const int pos = c & 3;
                dst[c] = (pos == 0) ? v0 : (pos == 1) ? v1 : (pos == 2) ? v2 : v3;
            }
        }
    }
}

// ---------------------------------------------------------------------------
// K_mid: 256 blocks; block bx -> 32x32 tile of MtotT = (W1 @ outW)^T bf16.
//        Blocks 0..15 (bm==0) also: btot[bn+n] = sum_k bvec[k]*Bs[n][k] + outb.
// ---------------------------------------------------------------------------
__global__ __launch_bounds__(512) void k_mid(const float* __restrict__ W1f,
                                             const float* __restrict__ outW,
                                             const float* __restrict__ bvec,
                                             const float* __restrict__ outb,
                                             unsigned short* __restrict__ MtotT,
                                             float* __restrict__ btot) {
    __shared__ __align__(16) char smem[65536];
    const int bx = blockIdx.x;
    const int tid = threadIdx.x;

    char* As = smem;             // [32 m][512 k] bf16, swz1024
    char* Bs = smem + 32768;     // [32 n][512 k] bf16, swz1024
    const int bm = (bx >> 4) * 32, bn = (bx & 15) * 32;

    // stage A: 2048 us8 chunks (32 rows x 64 chunks)
#pragma unroll
    for (int i = 0; i < 4; ++i) {
        int c = i * 512 + tid;
        int m = c >> 6, kc = (c & 63) * 8;
        const float* s = W1f + (size_t)(bm + m) * H + kc;
        fvec4 a0 = *(const fvec4*)s, a1 = *(const fvec4*)(s + 4);
        us8 hv;
        hv[0] = f2bf(a0.x); hv[1] = f2bf(a0.y); hv[2] = f2bf(a0.z); hv[3] = f2bf(a0.w);
        hv[4] = f2bf(a1.x); hv[5] = f2bf(a1.y); hv[6] = f2bf(a1.z); hv[7] = f2bf(a1.w);
        *(us8*)(As + swz1024(m, kc * 2)) = hv;
    }
    // stage B (transpose outW slice): 4096 chunks = 512 k x 8 n-quads
#pragma unroll
    for (int i = 0; i < 8; ++i) {
        int c = i * 512 + tid;
        int k = c >> 3, n4 = (c & 7) * 4;
        fvec4 v = *(const fvec4*)(outW + (size_t)k * H + bn + n4);
#pragma unroll
        for (int jj = 0; jj < 4; ++jj) {
            int n = n4 + jj;
            float vv = (jj == 0) ? v.x : (jj == 1) ? v.y : (jj == 2) ? v.z : v.w;
            *(unsigned short*)(Bs + swz1024(n, k * 2)) = f2bf(vv);
        }
    }
    __syncthreads();

    const int lane = tid & 63, w = tid >> 6;
    if (w < 4) {
        const int ro = lane & 15, ko8 = (lane >> 4) * 8;
        const int crow = (lane >> 4) * 4, ccol = lane & 15;
        const int mt = w >> 1, nt = w & 1;
        f32x4 acc = (f32x4)0.f;
#pragma unroll
        for (int ks = 0; ks < 16; ++ks) {
            const int kb = (ks * 32 + ko8) * 2;
            short8 af = *(const short8*)(As + swz1024(mt * 16 + ro, kb));
            short8 bf = *(const short8*)(Bs + swz1024(nt * 16 + ro, kb));
            acc = __builtin_amdgcn_mfma_f32_16x16x32_bf16(af, bf, acc, 0, 0, 0);
        }
        const int gcol = bn + nt * 16 + ccol;
        us4 hv;
        hv[0] = f2bf(acc[0]); hv[1] = f2bf(acc[1]);
        hv[2] = f2bf(acc[2]); hv[3] = f2bf(acc[3]);
        *(us4*)(MtotT + (size_t)gcol * H + bm + mt * 16 + crow) = hv;
    }

    // btot chunk: blocks with bm==0 own the outW^T panel for their bn
    if (bx < 16) {
        const int n = tid >> 4;          // 0..31 output within chunk
        const int ks = tid & 15;         // k-slice
        float part = 0.f;
#pragma unroll 8
        for (int i = 0; i < 32; ++i) {
            const int k = ks * 32 + i;
            unsigned short u = *(const unsigned short*)(Bs + swz1024(n, k * 2));
            part += bvec[k] * bf2f(u);
        }
        part += __shfl_xor(part, 1, 16);
        part += __shfl_xor(part, 2, 16);
        part += __shfl_xor(part, 4, 16);
        part += __shfl_xor(part, 8, 16);
        if (ks == 0) btot[bn + n] = part + outb[bn + n];
    }
}

// ---------------------------------------------------------------------------
// K_main: out[16384 x 512] = x @ Mtot + btot.  BM=64, BN=128, grid (256,4).
// 48 KB LDS + <=85 VGPR -> 3 blocks/CU (6 waves/SIMD). x is L3-resident.
// ---------------------------------------------------------------------------
__global__ __launch_bounds__(512, 6) void k_main(const float* __restrict__ A,
                                                 const unsigned short* __restrict__ Bt,
                                                 float* __restrict__ C,
                                                 const float* __restrict__ bias) {
    __shared__ __align__(16) unsigned short As[2][64 * 64];    // 2 x 8 KB, swizzled
    __shared__ __align__(16) unsigned short Bs[2][128 * 64];   // 2 x 16 KB, swizzled
    const int tid = threadIdx.x;
    const int bm = blockIdx.x * 64;
    const int bn = blockIdx.y * 128;
    const int lane = tid & 63, wid = tid >> 6;
    const int ro = lane & 15, ko8 = (lane >> 4) * 8;

    const int arr = tid >> 3, akc = (tid & 7) * 8;
    const float* aptr = A + (size_t)(bm + arr) * H + akc;
    const int awoff = ((arr * 128 + akc * 2) ^ ((arr & 7) << 4));

    const int brow = tid >> 3;   // 0..63; issue i covers panel rows i*64 + brow
    const char* bbase = (const char*)Bt + (size_t)(bn + brow) * 1024 +
                        (((tid & 7) * 16) ^ ((brow & 7) << 4));
    const int bdst = wid * 1024;

    f32x4 acc[4];
#pragma unroll
    for (int i = 0; i < 4; ++i) acc[i] = (f32x4)0.f;

    {   // prologue: tile 0 -> buf 0
        fvec4 a0 = *(const fvec4*)aptr, a1 = *(const fvec4*)(aptr + 4);
#pragma unroll
        for (int i = 0; i < 2; ++i)
            gll16(bbase + (size_t)i * 65536, (char*)&Bs[0][0] + i * 8192 + bdst);
        us8 hv;
        hv[0] = f2bf(a0.x); hv[1] = f2bf(a0.y); hv[2] = f2bf(a0.z); hv[3] = f2bf(a0.w);
        hv[4] = f2bf(a1.x); hv[5] = f2bf(a1.y); hv[6] = f2bf(a1.z); hv[7] = f2bf(a1.w);
        *(us8*)((char*)&As[0][0] + awoff) = hv;
    }
    __syncthreads();

    for (int t = 0; t < 8; ++t) {
        const int buf = t & 1;
        fvec4 pa0, pa1;
        if (t < 7) {   // issue next tile's loads first (hide under MFMA)
            pa0 = *(const fvec4*)(aptr + (t + 1) * 64);
            pa1 = *(const fvec4*)(aptr + (t + 1) * 64 + 4);
#pragma unroll
            for (int i = 0; i < 2; ++i)
                gll16(bbase + (size_t)i * 65536 + (t + 1) * 128,
                      (char*)&Bs[buf ^ 1][0] + i * 8192 + bdst);
        }
#pragma unroll
        for (int kk = 0; kk < 2; ++kk) {
            short8 af[4], bfr;
#pragma unroll
            for (int am = 0; am < 4; ++am) {
                int row = am * 16 + ro;
                af[am] = *(const short8*)((const char*)&As[buf][0] +
                         ((row * 128 + (kk * 32 + ko8) * 2) ^ ((row & 7) << 4)));
            }
            {
                int row = wid * 16 + ro;
                bfr = *(const short8*)((const char*)&Bs[buf][0] +
                      ((row * 128 + (kk * 32 + ko8) * 2) ^ ((row & 7) << 4)));
            }
#pragma unroll
            for (int am = 0; am < 4; ++am)
                acc[am] = __builtin_amdgcn_mfma_f32_16x16x32_bf16(af[am], bfr, acc[am], 0, 0, 0);
        }
        if (t < 7) {
            us8 hv;
            hv[0] = f2bf(pa0.x); hv[1] = f2bf(pa0.y); hv[2] = f2bf(pa0.z); hv[3] = f2bf(pa0.w);
            hv[4] = f2bf(pa1.x); hv[5] = f2bf(pa1.y); hv[6] = f2bf(pa1.z); hv[7] = f2bf(pa1.w);
            *(us8*)((char*)&As[buf ^ 1][0] + awoff) = hv;
        }
        __syncthreads();
    }

    const int crow = (lane >> 4) * 4, ccol = lane & 15;
#pragma unroll
    for (int am = 0; am < 4; ++am) {
        const int gcol = bn + wid * 16 + ccol;
        const float bv = bias[gcol];
        const int grow = bm + am * 16 + crow;
#pragma unroll
        for (int j = 0; j < 4; ++j)
            C[(size_t)(grow + j) * H + gcol] = acc[am][j] + bv;
    }
}

extern "C" void kernel_launch(void* const* d_in, const int* in_sizes, int n_in,
                              void* d_out, int out_size, void* d_ws, size_t ws_size,
                              hipStream_t stream) {
    const float* x      = (const float*)d_in[0];
    const float* in_W   = (const float*)d_in[1];
    const float* in_b   = (const float*)d_in[2];
    const float* ent_W  = (const float*)d_in[3];
    const float* ent_s  = (const float*)d_in[4];
    const float* sup_W  = (const float*)d_in[5];
    const float* sup_c  = (const float*)d_in[6];
    const float* cp     = (const float*)d_in[7];
    // d_in[8] = meas_ops == eye(512): exact no-op, skipped.
    const float* out_W  = (const float*)d_in[9];
    const float* out_b  = (const float*)d_in[10];
    float* out = (float*)d_out;

    char* ws = (char*)d_ws;
    const size_t MB = 1u << 20;
    if (ws_size < 16384 + MB + MB) return;

    float* btot = (float*)(ws);                                 // 512 f32
    float* bvec = (float*)(ws + 4096);                          // 512 f32
    float* W1f  = (float*)(ws + 16384);                         // 1 MB
    unsigned short* MtotT = (unsigned short*)(ws + 16384 + MB); // 0.5 MB

    k_prep<<<dim3(256), dim3(512), 0, stream>>>(in_W, in_b, ent_W, ent_s, sup_W,
                                                sup_c, cp, W1f, bvec);
    k_mid<<<dim3(256), dim3(512), 0, stream>>>(W1f, out_W, bvec, out_b, MtotT, btot);
    k_main<<<dim3(256, 4), dim3(512), 0, stream>>>(x, MtotT, out, btot);
}

// Round 15
// 37.701 us; speedup vs baseline: 1.2832x; 1.2832x over previous
//
#include <hip/hip_runtime.h>
#include <hip/hip_bf16.h>

// out = x @ Mtot + btot;  Mtot = L(in_W) @ out_W  (meas_ops == eye, exact skip)
// K_prep (513 blocks): W1f rows = L(in_W rows); row 512 -> bvec = L(in_b)
// K_mid  (256 blocks): one 32x32 MtotT tile each; blocks 0..15 also btot
// K_main (256x2 blocks): out = x @ Mtot + btot (BM=64 x BN=256, 2 blocks/CU)
// [R15 = verbatim revert to R13, the measured best: 38.2 us]

typedef float  fvec4 __attribute__((ext_vector_type(4)));
typedef float  f32x4 __attribute__((ext_vector_type(4)));
typedef short  short8 __attribute__((ext_vector_type(8)));
typedef unsigned short us8 __attribute__((ext_vector_type(8)));
typedef unsigned short us4 __attribute__((ext_vector_type(4)));

#define H 512
#define NL 3

__device__ __forceinline__ unsigned short f2bf(float f) {
    return __bfloat16_as_ushort(__float2bfloat16(f));
}
__device__ __forceinline__ float bf2f(unsigned short u) {
    return __uint_as_float((unsigned int)u << 16);
}
__device__ __forceinline__ void gll16(const void* g, void* l) {
    __builtin_amdgcn_global_load_lds((const __attribute__((address_space(1))) void*)g,
                                     (__attribute__((address_space(3))) void*)l, 16, 0, 0);
}
// 16B-chunk XOR swizzle for 1024B rows (bijective within row)
__device__ __forceinline__ int swz1024(int r, int byte) {
    return r * 1024 + (((byte >> 4) ^ (r & 7)) << 4) + (byte & 15);
}

// ---------------------------------------------------------------------------
// K_prep: one block per row of [in_W ; in_b] -> W1f / bvec  (proven flat form)
// ---------------------------------------------------------------------------
__global__ __launch_bounds__(512) void k_prep(const float* __restrict__ in_W,
                                              const float* __restrict__ in_b,
                                              const float* __restrict__ entW,
                                              const float* __restrict__ strength,
                                              const float* __restrict__ supW,
                                              const float* __restrict__ coeffs,
                                              const float* __restrict__ cp,
                                              float* __restrict__ W1f,
                                              float* __restrict__ bvec) {
    __shared__ float sseg[H];
    __shared__ float sval[H];
    __shared__ float sw[H];
    const int r = blockIdx.x;
    const int tid = threadIdx.x;
    const float* src = (r < H) ? (in_W + (size_t)r * H) : in_b;
    float* dst = (r < H) ? (W1f + (size_t)r * H) : bvec;

    sseg[tid] = src[tid];
    float wacc = 0.f;
#pragma unroll
    for (int s = 0; s < 8; ++s) wacc += coeffs[s] * supW[s * H + tid];
    sw[tid] = wacc;
    __syncthreads();

    // entangle: p = pair, j = col in pair; CNOT permutes cols 2<->3
    const int p = tid >> 7, j = tid & 127;
    const int jsrc = (j & 2) ? (j ^ 1) : j;
    const float* wcol = entW + p * (128 * 128) + jsrc;
    const float* seg = sseg + p * 128;
    float acc = 0.f;
#pragma unroll 8
    for (int i = 0; i < 128; ++i) acc += seg[i] * wcol[i * 128];
    acc *= strength[p];
    __syncthreads();
    sval[tid] = acc;
    __syncthreads();

    // quad-local gates
    const float is2 = 0.70710678118654752440f;
    const int q4 = tid & ~3;
    float v0 = sval[q4], v1 = sval[q4 + 1], v2 = sval[q4 + 2], v3 = sval[q4 + 3];
    float t0, t1, t2, t3;
    t0 = (v0 + v1) * is2; t1 = (v0 - v1) * is2;
    t2 = (v2 + v3) * is2; t3 = (v2 - v3) * is2;
    v0 = t0 * sw[q4]; v1 = t1 * sw[q4 + 1]; v2 = t2 * sw[q4 + 2]; v3 = t3 * sw[q4 + 3];
    const int qb = tid >> 6;
#pragma unroll
    for (int l = 0; l < NL; ++l) {
        float px = cp[l * 24 + qb * 3 + 0];
        float pz = cp[l * 24 + qb * 3 + 2];
        t0 = (v0 + v1) * is2; t1 = (v0 - v1) * is2;
        t2 = (v2 + v3) * is2; t3 = (v2 - v3) * is2;
        v0 = t0; v1 = t1; v2 = t2; v3 = t3;
        t0 = v0 + px * v1; t1 = v1 + px * v0;
        t2 = v2 + px * v3; t3 = v3 + px * v2;
        v0 = t0; v1 = t1; v2 = t2; v3 = t3;
        v0 *= (1.f + pz); v1 *= (1.f - pz);
        v2 *= (1.f + pz); v3 *= (1.f - pz);
        t0 = v2; v2 = v3; v3 = t0;   // CNOT
    }
    const int pos = tid & 3;
    dst[tid] = (pos == 0) ? v0 : (pos == 1) ? v1 : (pos == 2) ? v2 : v3;
}

// ---------------------------------------------------------------------------
// K_mid: 256 blocks; block bx -> 32x32 tile of MtotT = (W1 @ outW)^T bf16.
//        Blocks 0..15 (bm==0) also: btot[bn+n] = sum_k bvec[k]*Bs[n][k] + outb.
// ---------------------------------------------------------------------------
__global__ __launch_bounds__(512) void k_mid(const float* __restrict__ W1f,
                                             const float* __restrict__ outW,
                                             const float* __restrict__ bvec,
                                             const float* __restrict__ outb,
                                             unsigned short* __restrict__ MtotT,
                                             float* __restrict__ btot) {
    __shared__ __align__(16) char smem[65536];
    const int bx = blockIdx.x;
    const int tid = threadIdx.x;

    char* As = smem;             // [32 m][512 k] bf16, swz1024
    char* Bs = smem + 32768;     // [32 n][512 k] bf16, swz1024
    const int bm = (bx >> 4) * 32, bn = (bx & 15) * 32;

    // stage A: 2048 us8 chunks (32 rows x 64 chunks)
#pragma unroll
    for (int i = 0; i < 4; ++i) {
        int c = i * 512 + tid;
        int m = c >> 6, kc = (c & 63) * 8;
        const float* s = W1f + (size_t)(bm + m) * H + kc;
        fvec4 a0 = *(const fvec4*)s, a1 = *(const fvec4*)(s + 4);
        us8 hv;
        hv[0] = f2bf(a0.x); hv[1] = f2bf(a0.y); hv[2] = f2bf(a0.z); hv[3] = f2bf(a0.w);
        hv[4] = f2bf(a1.x); hv[5] = f2bf(a1.y); hv[6] = f2bf(a1.z); hv[7] = f2bf(a1.w);
        *(us8*)(As + swz1024(m, kc * 2)) = hv;
    }
    // stage B (transpose outW slice): 4096 chunks = 512 k x 8 n-quads
#pragma unroll
    for (int i = 0; i < 8; ++i) {
        int c = i * 512 + tid;
        int k = c >> 3, n4 = (c & 7) * 4;
        fvec4 v = *(const fvec4*)(outW + (size_t)k * H + bn + n4);
#pragma unroll
        for (int jj = 0; jj < 4; ++jj) {
            int n = n4 + jj;
            float vv = (jj == 0) ? v.x : (jj == 1) ? v.y : (jj == 2) ? v.z : v.w;
            *(unsigned short*)(Bs + swz1024(n, k * 2)) = f2bf(vv);
        }
    }
    __syncthreads();

    const int lane = tid & 63, w = tid >> 6;
    if (w < 4) {
        const int ro = lane & 15, ko8 = (lane >> 4) * 8;
        const int crow = (lane >> 4) * 4, ccol = lane & 15;
        const int mt = w >> 1, nt = w & 1;
        f32x4 acc = (f32x4)0.f;
#pragma unroll
        for (int ks = 0; ks < 16; ++ks) {
            const int kb = (ks * 32 + ko8) * 2;
            short8 af = *(const short8*)(As + swz1024(mt * 16 + ro, kb));
            short8 bf = *(const short8*)(Bs + swz1024(nt * 16 + ro, kb));
            acc = __builtin_amdgcn_mfma_f32_16x16x32_bf16(af, bf, acc, 0, 0, 0);
        }
        const int gcol = bn + nt * 16 + ccol;
        us4 hv;
        hv[0] = f2bf(acc[0]); hv[1] = f2bf(acc[1]);
        hv[2] = f2bf(acc[2]); hv[3] = f2bf(acc[3]);
        *(us4*)(MtotT + (size_t)gcol * H + bm + mt * 16 + crow) = hv;
    }

    // btot chunk: blocks with bm==0 own the outW^T panel for their bn
    if (bx < 16) {
        const int n = tid >> 4;          // 0..31 output within chunk
        const int ks = tid & 15;         // k-slice
        float part = 0.f;
#pragma unroll 8
        for (int i = 0; i < 32; ++i) {
            const int k = ks * 32 + i;
            unsigned short u = *(const unsigned short*)(Bs + swz1024(n, k * 2));
            part += bvec[k] * bf2f(u);
        }
        part += __shfl_xor(part, 1, 16);
        part += __shfl_xor(part, 2, 16);
        part += __shfl_xor(part, 4, 16);
        part += __shfl_xor(part, 8, 16);
        if (ks == 0) btot[bn + n] = part + outb[bn + n];
    }
}

// ---------------------------------------------------------------------------
// K_main: out[16384 x 512] = x @ Mtot + btot.  BM=64, BN=256, grid (256,2).
// 80 KB LDS -> 2 blocks/CU (4 waves/SIMD). x L3-resident; read 2x is free.
// ---------------------------------------------------------------------------
__global__ __launch_bounds__(512, 4) void k_main(const float* __restrict__ A,
                                                 const unsigned short* __restrict__ Bt,
                                                 float* __restrict__ C,
                                                 const float* __restrict__ bias) {
    __shared__ __align__(16) unsigned short As[2][64 * 64];    // 2 x 8 KB, swizzled
    __shared__ __align__(16) unsigned short Bs[2][256 * 64];   // 2 x 32 KB, swizzled
    const int tid = threadIdx.x;
    const int bm = blockIdx.x * 64;
    const int bn = blockIdx.y * 256;
    const int lane = tid & 63, wid = tid >> 6;
    const int ro = lane & 15, ko8 = (lane >> 4) * 8;

    const int arr = tid >> 3, akc = (tid & 7) * 8;
    const float* aptr = A + (size_t)(bm + arr) * H + akc;
    const int awoff = ((arr * 128 + akc * 2) ^ ((arr & 7) << 4));

    const int brow = tid >> 3;   // 0..63; issue i covers rows i*64+brow of the 256-panel
    const char* bbase = (const char*)Bt + (size_t)(bn + brow) * 1024 +
                        (((tid & 7) * 16) ^ ((brow & 7) << 4));
    const int bdst = wid * 1024;

    f32x4 acc[4][2];
#pragma unroll
    for (int i = 0; i < 4; ++i)
#pragma unroll
        for (int j = 0; j < 2; ++j) acc[i][j] = (f32x4)0.f;

    {   // prologue: tile 0 -> buf 0
        fvec4 a0 = *(const fvec4*)aptr, a1 = *(const fvec4*)(aptr + 4);
#pragma unroll
        for (int i = 0; i < 4; ++i)
            gll16(bbase + (size_t)i * 65536, (char*)&Bs[0][0] + i * 8192 + bdst);
        us8 hv;
        hv[0] = f2bf(a0.x); hv[1] = f2bf(a0.y); hv[2] = f2bf(a0.z); hv[3] = f2bf(a0.w);
        hv[4] = f2bf(a1.x); hv[5] = f2bf(a1.y); hv[6] = f2bf(a1.z); hv[7] = f2bf(a1.w);
        *(us8*)((char*)&As[0][0] + awoff) = hv;
    }
    __syncthreads();

    for (int t = 0; t < 8; ++t) {
        const int buf = t & 1;
        fvec4 pa0, pa1;
        if (t < 7) {   // issue next tile's loads first (hide under MFMA)
            pa0 = *(const fvec4*)(aptr + (t + 1) * 64);
            pa1 = *(const fvec4*)(aptr + (t + 1) * 64 + 4);
#pragma unroll
            for (int i = 0; i < 4; ++i)
                gll16(bbase + (size_t)i * 65536 + (t + 1) * 128,
                      (char*)&Bs[buf ^ 1][0] + i * 8192 + bdst);
        }
#pragma unroll
        for (int kk = 0; kk < 2; ++kk) {
            short8 af[4], bfr[2];
#pragma unroll
            for (int am = 0; am < 4; ++am) {
                int row = am * 16 + ro;
                af[am] = *(const short8*)((const char*)&As[buf][0] +
                         ((row * 128 + (kk * 32 + ko8) * 2) ^ ((row & 7) << 4)));
            }
#pragma unroll
            for (int bj = 0; bj < 2; ++bj) {
                int row = wid * 32 + bj * 16 + ro;
                bfr[bj] = *(const short8*)((const char*)&Bs[buf][0] +
                          ((row * 128 + (kk * 32 + ko8) * 2) ^ ((row & 7) << 4)));
            }
#pragma unroll
            for (int am = 0; am < 4; ++am)
#pragma unroll
                for (int bj = 0; bj < 2; ++bj)
                    acc[am][bj] = __builtin_amdgcn_mfma_f32_16x16x32_bf16(af[am], bfr[bj], acc[am][bj], 0, 0, 0);
        }
        if (t < 7) {
            us8 hv;
            hv[0] = f2bf(pa0.x); hv[1] = f2bf(pa0.y); hv[2] = f2bf(pa0.z); hv[3] = f2bf(pa0.w);
            hv[4] = f2bf(pa1.x); hv[5] = f2bf(pa1.y); hv[6] = f2bf(pa1.z); hv[7] = f2bf(pa1.w);
            *(us8*)((char*)&As[buf ^ 1][0] + awoff) = hv;
        }
        __syncthreads();
    }

    const int crow = (lane >> 4) * 4, ccol = lane & 15;
#pragma unroll
    for (int am = 0; am < 4; ++am)
#pragma unroll
        for (int bj = 0; bj < 2; ++bj) {
            const int gcol = bn + wid * 32 + bj * 16 + ccol;
            const float bv = bias[gcol];
            const int grow = bm + am * 16 + crow;
#pragma unroll
            for (int j = 0; j < 4; ++j)
                C[(size_t)(grow + j) * H + gcol] = acc[am][bj][j] + bv;
        }
}

extern "C" void kernel_launch(void* const* d_in, const int* in_sizes, int n_in,
                              void* d_out, int out_size, void* d_ws, size_t ws_size,
                              hipStream_t stream) {
    const float* x      = (const float*)d_in[0];
    const float* in_W   = (const float*)d_in[1];
    const float* in_b   = (const float*)d_in[2];
    const float* ent_W  = (const float*)d_in[3];
    const float* ent_s  = (const float*)d_in[4];
    const float* sup_W  = (const float*)d_in[5];
    const float* sup_c  = (const float*)d_in[6];
    const float* cp     = (const float*)d_in[7];
    // d_in[8] = meas_ops == eye(512): exact no-op, skipped.
    const float* out_W  = (const float*)d_in[9];
    const float* out_b  = (const float*)d_in[10];
    float* out = (float*)d_out;

    char* ws = (char*)d_ws;
    const size_t MB = 1u << 20;
    if (ws_size < 16384 + MB + MB) return;

    float* btot = (float*)(ws);                                 // 512 f32
    float* bvec = (float*)(ws + 4096);                          // 512 f32
    float* W1f  = (float*)(ws + 16384);                         // 1 MB
    unsigned short* MtotT = (unsigned short*)(ws + 16384 + MB); // 0.5 MB

    k_prep<<<dim3(513), dim3(512), 0, stream>>>(in_W, in_b, ent_W, ent_s, sup_W,
                                                sup_c, cp, W1f, bvec);
    k_mid<<<dim3(256), dim3(512), 0, stream>>>(W1f, out_W, bvec, out_b, MtotT, btot);
    k_main<<<dim3(256, 2), dim3(512), 0, stream>>>(x, MtotT, out, btot);
}